// Round 11
// baseline (231.127 us; speedup 1.0000x reference)
//
#include <hip/hip_runtime.h>
#include <hip/hip_bf16.h>

// CausalInterventionAttention: B=2, S=2048, D=1024, H=16, HD=64
// Round 11: attn 2-wave/64-row blocks (grid 1024, single-buf KV, 6 blk/CU);
// gemm_qkv 128x64 tiles (grid 1536, 6 blk/CU).

typedef __attribute__((ext_vector_type(8))) short bf16x8;
typedef __attribute__((ext_vector_type(4))) float f32x4;

__device__ __forceinline__ unsigned short f2b(float f) {
  union { float f; unsigned u; } x; x.f = f;
  unsigned r = x.u + 0x7FFFu + ((x.u >> 16) & 1u);  // RNE
  return (unsigned short)(r >> 16);
}

__device__ __forceinline__ unsigned short f2b_n(float f) {
  __hip_bfloat16 h = __float2bfloat16(f);
  union { __hip_bfloat16 h; unsigned short u; } c; c.h = h;
  return c.u;
}

__device__ __forceinline__ float fexp2(float x) {
#if __has_builtin(__builtin_amdgcn_exp2f)
  return __builtin_amdgcn_exp2f(x);
#else
  return __expf(x * 0.6931471805599453f);
#endif
}

__device__ __forceinline__ void gl_lds16(const unsigned short* g, unsigned short* l) {
  __builtin_amdgcn_global_load_lds(
      (const __attribute__((address_space(1))) unsigned int*)g,
      (__attribute__((address_space(3))) unsigned int*)l, 16, 0, 0);
}

// ---------------- conversion kernels ----------------

__global__ __launch_bounds__(256) void cvt_x_kernel(const float* __restrict__ x,
                                                    unsigned short* __restrict__ xb, int n4) {
  int i = blockIdx.x * 256 + threadIdx.x;
  if (i >= n4) return;
  float4 v = ((const float4*)x)[i];
  ushort4 o;
  o.x = f2b(v.x); o.y = f2b(v.y); o.z = f2b(v.z); o.w = f2b(v.w);
  ((ushort4*)xb)[i] = o;
}

// All 4 weights: W [1024 k][1024 n] fp32 -> Wt [1024 n][1024 k] bf16 (packed writes)
__global__ __launch_bounds__(256) void cvt_w4_kernel(
    const float* __restrict__ W0, const float* __restrict__ W1,
    const float* __restrict__ W2, const float* __restrict__ W3,
    unsigned short* __restrict__ WtBase) {
  __shared__ float t[64][33];
  const int z = blockIdx.z;
  const float* W = z == 0 ? W0 : (z == 1 ? W1 : (z == 2 ? W2 : W3));
  unsigned short* Wt = WtBase + (size_t)z * 1048576;
  const int k0 = blockIdx.x * 64, n0 = blockIdx.y * 32;
  const int tx = threadIdx.x, ty = threadIdx.y;  // block (32,8)
  #pragma unroll
  for (int i = 0; i < 8; i++)
    t[ty + i * 8][tx] = W[(size_t)(k0 + ty + i * 8) * 1024 + n0 + tx];
  __syncthreads();
  #pragma unroll
  for (int i = 0; i < 4; i++) {
    const int n = ty + i * 8;
    ushort2 pk;
    pk.x = f2b(t[tx * 2][n]);
    pk.y = f2b(t[tx * 2 + 1][n]);
    *(ushort2*)&Wt[(size_t)(n0 + n) * 1024 + k0 + tx * 2] = pk;
  }
}

// ---------------- fused QKV GEMM 128x64 (grid 1536 = 6 blocks/CU) ----------------
// Bt = [3072 n][1024 k]; n-range selects dst q/k/vt + bias.
__global__ __launch_bounds__(256, 4) void gemm_qkv(
    const unsigned short* __restrict__ A, const unsigned short* __restrict__ Bt,
    const float* __restrict__ b0, const float* __restrict__ b1, const float* __restrict__ b2,
    unsigned short* __restrict__ dq, unsigned short* __restrict__ dk,
    unsigned short* __restrict__ dv) {
  __shared__ unsigned short As[2][4096];  // [128][32]
  __shared__ unsigned short Bs[2][2048];  // [64][32]
  const int tid = threadIdx.x;
  const int w = tid >> 6, lane = tid & 63;
  const int li = lane & 15, g = lane >> 4;
  const int m0 = blockIdx.x * 128, n0 = blockIdx.y * 64;

  const int srow0 = w * 32 + (lane >> 2), srow1 = srow0 + 16;
  const int srowB = w * 16 + (lane >> 2);
  const int scol = (lane & 3) * 8;
  const unsigned short* gA0 = A + (size_t)(m0 + srow0) * 1024 + scol;
  const unsigned short* gA1 = A + (size_t)(m0 + srow1) * 1024 + scol;
  const unsigned short* gB0 = Bt + (size_t)(n0 + srowB) * 1024 + scol;

  f32x4 acc[2][4];
  #pragma unroll
  for (int i = 0; i < 2; i++)
    #pragma unroll
    for (int j = 0; j < 4; j++) acc[i][j] = (f32x4){0.f, 0.f, 0.f, 0.f};

#define QSTAGE(bufi, kt)                                 \
  {                                                      \
    const int ko = (kt) * 32;                            \
    gl_lds16(gA0 + ko, &As[bufi][w * 1024]);             \
    gl_lds16(gA1 + ko, &As[bufi][w * 1024 + 512]);       \
    gl_lds16(gB0 + ko, &Bs[bufi][w * 512]);              \
  }

  QSTAGE(0, 0)
  int buf = 0;
  for (int kt = 0; kt < 32; kt++) {
    __syncthreads();
    if (kt + 1 < 32) QSTAGE(buf ^ 1, kt + 1)
    bf16x8 af[2], bfr[4];
    #pragma unroll
    for (int mt = 0; mt < 2; mt++)
      af[mt] = *(const bf16x8*)&As[buf][(w * 32 + mt * 16 + li) * 32 + g * 8];
    #pragma unroll
    for (int nt = 0; nt < 4; nt++)
      bfr[nt] = *(const bf16x8*)&Bs[buf][(nt * 16 + li) * 32 + g * 8];
    #pragma unroll
    for (int mt = 0; mt < 2; mt++)
      #pragma unroll
      for (int nt = 0; nt < 4; nt++)
        acc[mt][nt] = __builtin_amdgcn_mfma_f32_16x16x32_bf16(af[mt], bfr[nt], acc[mt][nt], 0, 0, 0);
    buf ^= 1;
  }
#undef QSTAGE

  const int sel = n0 >> 10;  // 64-tiles never straddle the 1024 boundaries
  const float* bp = sel == 0 ? b0 : (sel == 1 ? b1 : b2);
  unsigned short* dst = sel == 0 ? dq : (sel == 1 ? dk : dv);
  #pragma unroll
  for (int nt = 0; nt < 4; nt++) {
    const int gc = n0 + nt * 16 + li;
    const int c = gc & 1023, h = c >> 6, d = c & 63;
    const float bv = bp[c];
    #pragma unroll
    for (int mt = 0; mt < 2; mt++) {
      const int base = m0 + w * 32 + mt * 16 + g * 4;  // 4-aligned, no 2048-straddle
      const int bb = base >> 11, s = base & 2047;
      if (sel < 2) {
        #pragma unroll
        for (int r = 0; r < 4; r++)
          dst[((size_t)(bb * 16 + h) * 2048 + s + r) * 64 + d] = f2b_n(acc[mt][nt][r] + bv);
      } else {  // Vt [bh][d][s]: 4 consecutive s -> one 8B store
        ushort4 pk;
        pk.x = f2b_n(acc[mt][nt][0] + bv);
        pk.y = f2b_n(acc[mt][nt][1] + bv);
        pk.z = f2b_n(acc[mt][nt][2] + bv);
        pk.w = f2b_n(acc[mt][nt][3] + bv);
        *(ushort4*)&dst[((size_t)(bb * 16 + h) * 64 + d) * 2048 + s] = pk;
      }
    }
  }
}

// ---------------- out-proj GEMM 128x64 ----------------
__global__ __launch_bounds__(256) void gemm_out(
    const unsigned short* __restrict__ A, const unsigned short* __restrict__ Bt,
    const float* __restrict__ bias, float* __restrict__ dout) {
  __shared__ unsigned short As[2][4096];  // [128][32]
  __shared__ unsigned short Bs[2][2048];  // [64][32]
  const int tid = threadIdx.x;
  const int w = tid >> 6, lane = tid & 63;
  const int li = lane & 15, g = lane >> 4;
  const int m0 = blockIdx.x * 128, n0 = blockIdx.y * 64;

  const int srow0 = w * 32 + (lane >> 2), srow1 = srow0 + 16;
  const int srowB = w * 16 + (lane >> 2);
  const int scol = (lane & 3) * 8;
  const unsigned short* gA0 = A + (size_t)(m0 + srow0) * 1024 + scol;
  const unsigned short* gA1 = A + (size_t)(m0 + srow1) * 1024 + scol;
  const unsigned short* gB0 = Bt + (size_t)(n0 + srowB) * 1024 + scol;

  f32x4 acc[2][4];
  #pragma unroll
  for (int i = 0; i < 2; i++)
    #pragma unroll
    for (int j = 0; j < 4; j++) acc[i][j] = (f32x4){0.f, 0.f, 0.f, 0.f};

#define OSTAGE(bufi, kt)                                 \
  {                                                      \
    const int ko = (kt) * 32;                            \
    gl_lds16(gA0 + ko, &As[bufi][w * 1024]);             \
    gl_lds16(gA1 + ko, &As[bufi][w * 1024 + 512]);       \
    gl_lds16(gB0 + ko, &Bs[bufi][w * 512]);              \
  }

  OSTAGE(0, 0)
  int buf = 0;
  for (int kt = 0; kt < 32; kt++) {
    __syncthreads();
    if (kt + 1 < 32) OSTAGE(buf ^ 1, kt + 1)
    bf16x8 af[2], bfr[4];
    #pragma unroll
    for (int mt = 0; mt < 2; mt++)
      af[mt] = *(const bf16x8*)&As[buf][(w * 32 + mt * 16 + li) * 32 + g * 8];
    #pragma unroll
    for (int nt = 0; nt < 4; nt++)
      bfr[nt] = *(const bf16x8*)&Bs[buf][(nt * 16 + li) * 32 + g * 8];
    #pragma unroll
    for (int mt = 0; mt < 2; mt++)
      #pragma unroll
      for (int nt = 0; nt < 4; nt++)
        acc[mt][nt] = __builtin_amdgcn_mfma_f32_16x16x32_bf16(af[mt], bfr[nt], acc[mt][nt], 0, 0, 0);
    buf ^= 1;
  }
#undef OSTAGE

  #pragma unroll
  for (int nt = 0; nt < 4; nt++) {
    const int gc = n0 + nt * 16 + li;
    const float bv = bias[gc];
    #pragma unroll
    for (int mt = 0; mt < 2; mt++)
      #pragma unroll
      for (int r = 0; r < 4; r++) {
        const int gr = m0 + w * 32 + mt * 16 + g * 4 + r;
        dout[(size_t)gr * 1024 + gc] = acc[mt][nt][r] + bv;
      }
  }
}

// ---------------- flash attention ----------------
// grid 1024 (remapped); block 128 (2 waves x 32 q-rows), KVBLK=64 single-buffered.
// Max-free softmax; 24 KB LDS -> 6 blocks/CU = 12 waves/CU.
__global__ __launch_bounds__(128, 3) void attn_kernel(
    const unsigned short* __restrict__ qb, const unsigned short* __restrict__ kb,
    const unsigned short* __restrict__ vtb, const int* __restrict__ cause,
    const int* __restrict__ effect, const float* __restrict__ strength,
    unsigned short* __restrict__ attb) {
  __shared__ unsigned short Ks[4096];     // [64 key][64 d] swizzled
  __shared__ unsigned short Vs[4096];     // [64 d][64 key] swizzled
  __shared__ unsigned short Pl[2][2048];  // per-wave [32 q][64 k] swizzled
  const int tid = threadIdx.x;
  const int w = tid >> 6, lane = tid & 63;
  const int g = lane >> 4, li = lane & 15;
  // XCD-bijective remap: all 32 q-blocks of one bh land on one XCD (lid%8 const)
  const int lid = blockIdx.y * 32 + blockIdx.x;       // [0,1024)
  const int bh = ((lid & 7) << 2) | ((lid >> 3) & 3);
  const int qblk = lid >> 5;                          // [0,32)
  const int b = bh >> 4, h = bh & 15;
  const int q0 = qblk * 64 + w * 32;

  const unsigned short* kbp = kb + (size_t)bh * 2048 * 64;
  const unsigned short* vbp = vtb + (size_t)bh * 64 * 2048;

  bf16x8 qa[2][2];
  #pragma unroll
  for (int i = 0; i < 2; i++) {
    const unsigned short* qrow = qb + ((size_t)bh * 2048 + q0 + i * 16 + li) * 64 + g * 8;
    qa[i][0] = *(const bf16x8*)(qrow);
    qa[i][1] = *(const bf16x8*)(qrow + 32);
  }

  const float LOG2E = 1.44269504f;
  const float fmask = 1.0f - 0.5f * strength[0];
  const float c0s2 = 0.125f * LOG2E;
  const float c1s2 = c0s2 * fmask;
  float mrr[2][4];
  #pragma unroll
  for (int i = 0; i < 2; i++)
    #pragma unroll
    for (int r = 0; r < 4; r++)
      mrr[i][r] = cause[b * 2048 + q0 + i * 16 + g * 4 + r] ? c1s2 : c0s2;
  const int* eff = effect + b * 2048;

  // staging: per wave 4 K-segs + 4 V-segs of 1KB (8 rows x 128B); source pre-XORed
  const int rowin = lane >> 3;                      // 0..7
  const int cs = (((lane & 7) ^ rowin) * 8);        // shorts
  const unsigned short* kg[4];
  const unsigned short* vg[4];
  #pragma unroll
  for (int j = 0; j < 4; j++) {
    const int seg = w * 4 + j;
    const int row = seg * 8 + rowin;
    kg[j] = kbp + (size_t)row * 64 + cs;
    vg[j] = vbp + (size_t)row * 2048 + cs;
  }

#define ASTAGE(t)                                            \
  {                                                          \
    _Pragma("unroll")                                        \
    for (int j = 0; j < 4; j++) {                            \
      gl_lds16(kg[j] + (size_t)(t) * 4096, &Ks[(w * 4 + j) * 512]); \
      gl_lds16(vg[j] + (t) * 64, &Vs[(w * 4 + j) * 512]);    \
    }                                                        \
  }

  // swizzled frag-read columns (shorts): row&7 == li&7 for all frag reads
  const int swz = (li & 7) << 4;  // bytes
  const int col0 = ((g * 16) ^ swz) >> 1;
  const int col1 = ((64 + g * 16) ^ swz) >> 1;

  float l[2][4];
  f32x4 acc[2][4];
  #pragma unroll
  for (int i = 0; i < 2; i++) {
    #pragma unroll
    for (int r = 0; r < 4; r++) l[i][r] = 0.f;
    #pragma unroll
    for (int c = 0; c < 4; c++) acc[i][c] = (f32x4){0.f, 0.f, 0.f, 0.f};
  }

  for (int t = 0; t < 32; t++) {
    if (t) __syncthreads();   // all waves done reading tile t-1
    ASTAGE(t)
    __syncthreads();          // tile t staged (drains vmcnt)
    const int kk = t * 64;
    #pragma unroll
    for (int s = 0; s < 4; s++) {
      const bf16x8 kf0 = *(const bf16x8*)&Ks[s * 1024 + li * 64 + col0];
      const bf16x8 kf1 = *(const bf16x8*)&Ks[s * 1024 + li * 64 + col1];
      const bool eb = eff[kk + s * 16 + li] != 0;
      #pragma unroll
      for (int i = 0; i < 2; i++) {
        f32x4 z = (f32x4){0.f, 0.f, 0.f, 0.f};
        z = __builtin_amdgcn_mfma_f32_16x16x32_bf16(qa[i][0], kf0, z, 0, 0, 0);
        z = __builtin_amdgcn_mfma_f32_16x16x32_bf16(qa[i][1], kf1, z, 0, 0, 0);
        #pragma unroll
        for (int r = 0; r < 4; r++) {
          const float p = fexp2(z[r] * (eb ? mrr[i][r] : c0s2));
          l[i][r] += p;
          const int row = i * 16 + g * 4 + r;
          Pl[w][row * 64 + (((s * 32 + li * 2) ^ ((row & 7) << 4)) >> 1)] = f2b_n(p);
        }
      }
    }
    bf16x8 pa[2][2];
    #pragma unroll
    for (int i = 0; i < 2; i++) {
      pa[i][0] = *(const bf16x8*)&Pl[w][(i * 16 + li) * 64 + col0];
      pa[i][1] = *(const bf16x8*)&Pl[w][(i * 16 + li) * 64 + col1];
    }
    #pragma unroll
    for (int c = 0; c < 4; c++) {
      const bf16x8 vf0 = *(const bf16x8*)&Vs[c * 1024 + li * 64 + col0];
      const bf16x8 vf1 = *(const bf16x8*)&Vs[c * 1024 + li * 64 + col1];
      #pragma unroll
      for (int i = 0; i < 2; i++) {
        acc[i][c] = __builtin_amdgcn_mfma_f32_16x16x32_bf16(pa[i][0], vf0, acc[i][c], 0, 0, 0);
        acc[i][c] = __builtin_amdgcn_mfma_f32_16x16x32_bf16(pa[i][1], vf1, acc[i][c], 0, 0, 0);
      }
    }
  }
#undef ASTAGE

  // single final l-reduce across the 16 lanes of each group
  #pragma unroll
  for (int off = 1; off < 16; off <<= 1)
    #pragma unroll
    for (int i = 0; i < 2; i++)
      #pragma unroll
      for (int r = 0; r < 4; r++) l[i][r] += __shfl_xor(l[i][r], off, 16);
  #pragma unroll
  for (int i = 0; i < 2; i++)
    #pragma unroll
    for (int r = 0; r < 4; r++) l[i][r] = 1.0f / l[i][r];
  #pragma unroll
  for (int i = 0; i < 2; i++)
    #pragma unroll
    for (int c = 0; c < 4; c++)
      #pragma unroll
      for (int r = 0; r < 4; r++) {
        const int row = q0 + i * 16 + g * 4 + r;
        attb[(size_t)(b * 2048 + row) * 1024 + h * 64 + c * 16 + li] = f2b_n(acc[i][c][r] * l[i][r]);
      }
}

// ---------------- launch ----------------

extern "C" void kernel_launch(void* const* d_in, const int* in_sizes, int n_in,
                              void* d_out, int out_size, void* d_ws, size_t ws_size,
                              hipStream_t stream) {
  (void)in_sizes; (void)n_in; (void)out_size; (void)ws_size;
  const float* x = (const float*)d_in[0];
  const int* cause = (const int*)d_in[1];
  const int* effect = (const int*)d_in[2];
  const float* strength = (const float*)d_in[3];
  const float* Wq = (const float*)d_in[4];
  const float* bq = (const float*)d_in[5];
  const float* Wk = (const float*)d_in[6];
  const float* bk = (const float*)d_in[7];
  const float* Wv = (const float*)d_in[8];
  const float* bv = (const float*)d_in[9];
  const float* Wo = (const float*)d_in[10];
  const float* bo = (const float*)d_in[11];
  float* out = (float*)d_out;

  char* ws = (char*)d_ws;
  unsigned short* xb  = (unsigned short*)(ws);                // 8 MB
  unsigned short* wqt = (unsigned short*)(ws + (8u << 20));   // 2 MB each, q|k|v|o contiguous
  unsigned short* qbf = (unsigned short*)(ws + (16u << 20));  // 8 MB
  unsigned short* kbf = (unsigned short*)(ws + (24u << 20));  // 8 MB
  unsigned short* vtb = (unsigned short*)(ws + (32u << 20));  // 8 MB
  unsigned short* wot = wqt + 3u * 1048576u;
  unsigned short* attb = xb;  // reuse after projections

  cvt_x_kernel<<<4096, 256, 0, stream>>>(x, xb, 1048576);
  cvt_w4_kernel<<<dim3(16, 32, 4), dim3(32, 8), 0, stream>>>(Wq, Wk, Wv, Wo, wqt);

  gemm_qkv<<<dim3(32, 48), 256, 0, stream>>>(xb, wqt, bq, bk, bv, qbf, kbf, vtb);
  attn_kernel<<<dim3(32, 32), 128, 0, stream>>>(qbf, kbf, vtb, cause, effect, strength, attb);
  gemm_out<<<dim3(32, 16), 256, 0, stream>>>(attb, wot, bo, out);
}